// Round 16
// baseline (191.240 us; speedup 1.0000x reference)
//
#include <hip/hip_runtime.h>

// Sinkhorn (dustbin-augmented), fp8 MFMA edition v16.
// = v15's validated structure (512 threads / 8 waves, 2 blocks/CU,
//   waves_per_eu(4,4) 128-reg budget, fp8 scale-16 loop, fragment-decode
//   epilogue) + SINGLE-fetch prologue: scores are read from HBM once,
//   converted to fp8 in registers, staged through a 68 KB col-major LDS
//   tile (stride 272 B), and gathered into the pinned esA/esB fragments.
//   v15 read the input twice (row-wise + col-wise straight from global:
//   FETCH 131 MB) -- that was its regression vs v9.
//
// State (validated v8..v15):
//   EU_i  = 1/(sum_j es_ij*EV_j + A*evd)        es = 2^{s*log2e}
//   eud_s = Cs/(sum_j EV_j + evd),  Cs = 2^8/A, A = 2^{alpha*log2e}
//   EV_j  = 1/(sum_i es_ij*EU_i + A*eud_s)
//   evd'  = Cs/(sum_i EU_i + eud_s)
//   Z core = (log2 es + log2 EU + log2 EV)*ln2  (dustbins use alpha2)
// fp8 carries es, 16*EU, 16*EV (accs 16x true, recovered via tdv16/tdu16).
//
// Maps: wave w (0..7), lane l = l15 + 16g, strip r in {0,1}:
//   row_r / col_r = 16w + l15 + 128r
//   esA[r][s] byte j = es[row_r][32s+8g+j]     (A row strip)
//   esB[r][s] byte j = es[32s+8g+j][col_r]     (B col strip)
// C/D: col=lane&15, row=(lane>>4)*4+reg (HW-measured, dtype-independent).

typedef float floatx4 __attribute__((ext_vector_type(4)));
typedef unsigned int uint2v __attribute__((ext_vector_type(2)));
typedef _Float16 half8v __attribute__((ext_vector_type(8)));

#define CSTRIDE 272   // fp8 tile column stride in bytes (16-aligned)

constexpr float L2E = 1.4426950408889634f;
constexpr float LN2 = 0.6931471805599453f;

__device__ __forceinline__ float flog2(float x) { return __builtin_amdgcn_logf(x); }
__device__ __forceinline__ float fexp2(float x) { return __builtin_amdgcn_exp2f(x); }

__device__ __forceinline__ float rcp_nr(float d) {
    float r = __builtin_amdgcn_rcpf(d);
    return r * fmaf(-d, r, 2.0f);
}

template <int CTRL>
__device__ __forceinline__ float dpp_add(float x) {
    int y = __builtin_amdgcn_update_dpp(0, __builtin_bit_cast(int, x), CTRL, 0xF, 0xF, true);
    return x + __builtin_bit_cast(float, y);
}
__device__ __forceinline__ float reduce16(float x) {
    x = dpp_add<0xB1>(x);    // xor 1
    x = dpp_add<0x4E>(x);    // xor 2
    x = dpp_add<0x124>(x);   // row_ror:4
    x = dpp_add<0x128>(x);   // row_ror:8
    return x;
}
__device__ __forceinline__ float xor16_add(float x) {
    int y = __builtin_amdgcn_ds_swizzle(__builtin_bit_cast(int, x), 0x401F);
    return x + __builtin_bit_cast(float, y);
}

// f32 -> OCP e4m3fn (x >= 0), round-half-up, clamp 448 (validated v14/v15).
__device__ __forceinline__ unsigned f32_to_e4m3(float x) {
    if (!(x > 0.0f)) return 0u;
    if (x < 0.015625f) {
        int mi = (int)fmaf(x, 512.0f, 0.5f);
        return (unsigned)mi;
    }
    unsigned u = __builtin_bit_cast(unsigned, x);
    unsigned r = u + 0x80000u;
    int e2 = (int)((r >> 23) & 255u) - 127;
    if (e2 > 8) return 0x7Eu;
    unsigned b = (unsigned)(((e2 + 7) << 3) | ((r >> 20) & 7u));
    if (b >= 0x7Fu) b = 0x7Eu;
    return b;
}
// e4m3fn byte -> f32 (non-negative)
__device__ __forceinline__ float dec_e4m3(unsigned b) {
    unsigned e = (b >> 3) & 15u, m = b & 7u;
    if (e == 0) return (float)m * 0.001953125f;      // m * 2^-9
    return __builtin_bit_cast(float, ((e + 120u) << 23) | (m << 20));
}

__global__ __launch_bounds__(512)
__attribute__((amdgpu_waves_per_eu(4, 4)))
void sinkhorn_kernel(const float* __restrict__ scores,
                     const float* __restrict__ alpha_p,
                     const int* __restrict__ iters_p,
                     float* __restrict__ out)
{
    const int bat = blockIdx.x;
    const int t   = threadIdx.x;
    const int w   = t >> 6;         // wave 0..7
    const int l   = t & 63;
    const int g   = (t >> 4) & 3;   // k-group within wave
    const int l15 = t & 15;

    const float alpha2 = alpha_p[0] * L2E;
    const float A  = fexp2(alpha2);
    const float Cs = fexp2(8.0f - alpha2);   // 2^8 / A
    const int iters = iters_p[0];

    __shared__ __align__(16) unsigned char  es8T[256 * CSTRIDE];  // 68 KB fp8 tile
    __shared__ __align__(16) unsigned char  EV8a[288];            // fp8(16*EV)
    __shared__ __align__(16) unsigned char  EU8a[288];            // fp8(16*EU)
    __shared__ __align__(16) unsigned short EUa[288];             // f16 EU
    __shared__ __align__(16) unsigned short EVa[288];             // f16 EV
    __shared__ __align__(16) float wsU[8];
    __shared__ __align__(16) float wsV[8];

    const float* S = scores + ((size_t)bat << 16);

    // ---------- prologue: ONE coalesced pass, fp8 tile in LDS ----------
    {
        const int a  = t >> 5;   // 0..15 : rows [16a, 16a+16)
        const int bb = t & 31;   // cols bb + 32k, k = 0..7
        unsigned cb[8][4];
        #pragma unroll
        for (int k = 0; k < 8; ++k) {
            cb[k][0] = 0; cb[k][1] = 0; cb[k][2] = 0; cb[k][3] = 0;
        }
        const float* sp = S + (a << 12) + bb;
        #pragma unroll
        for (int r = 0; r < 16; ++r) {
            #pragma unroll
            for (int k = 0; k < 8; ++k) {
                const float x = sp[(r << 8) + (k << 5)];
                cb[k][r >> 2] |= f32_to_e4m3(fexp2(x * L2E)) << ((r & 3) << 3);
            }
        }
        #pragma unroll
        for (int k = 0; k < 8; ++k) {
            const int col = bb + (k << 5);
            *reinterpret_cast<uint4*>(&es8T[col * CSTRIDE + (a << 4)]) =
                make_uint4(cb[k][0], cb[k][1], cb[k][2], cb[k][3]);
        }
    }
    if (t < 64)  reinterpret_cast<unsigned*>(EV8a)[t] = 0x58585858u;  // fp8(16)=1.0*16
    if (t < 256) EVa[t] = 0x3C00;                                     // f16 1.0
    if (t < 8)   wsV[t] = 32.0f;                                      // 32 ones/wave
    __syncthreads();

    // ---------- gather fragments from the tile (asm-pinned) ----------
    long esA[2][8], esB[2][8];
    #pragma unroll
    for (int r = 0; r < 2; ++r) {
        const int row = (w << 4) + l15 + (r << 7);
        #pragma unroll
        for (int s = 0; s < 8; ++s) {
            unsigned lo = 0, hi = 0;
            #pragma unroll
            for (int j = 0; j < 8; ++j) {
                const unsigned b = es8T[((s << 5) + (g << 3) + j) * CSTRIDE + row];
                if (j < 4) lo |= b << (j << 3);
                else       hi |= b << ((j - 4) << 3);
            }
            uint2v p; p.x = lo; p.y = hi;
            esA[r][s] = __builtin_bit_cast(long, p);
            asm volatile("" : "+v"(esA[r][s]));
        }
    }
    #pragma unroll
    for (int r = 0; r < 2; ++r) {
        const int col = (w << 4) + l15 + (r << 7);
        #pragma unroll
        for (int s = 0; s < 8; ++s) {
            esB[r][s] = *reinterpret_cast<const long*>(
                &es8T[col * CSTRIDE + (s << 5) + (g << 3)]);
            asm volatile("" : "+v"(esB[r][s]));
        }
    }

    float evd = 1.0f, eud_s = 1.0f;

    // ---------- loop (v15 verbatim) ----------
    for (int it = 0; it < iters; ++it) {
        float sv = evd;
        {
            const floatx4* wv = reinterpret_cast<const floatx4*>(wsV);
            const floatx4 ss = wv[0] + wv[1];
            sv += (ss[0] + ss[1]) + (ss[2] + ss[3]);
        }
        eud_s = Cs * rcp_nr(sv);
        const float tdu16 = 16.0f * A * eud_s;
        const float tdv16 = 16.0f * A * evd;

        // p-phase
        floatx4 c00 = {0,0,0,0}, c01 = {0,0,0,0}, c10 = {0,0,0,0}, c11 = {0,0,0,0};
        #pragma unroll
        for (int s = 0; s < 4; ++s) {
            const long b0 = *reinterpret_cast<const long*>(&EV8a[((2*s) << 5) + (g << 3)]);
            const long b1 = *reinterpret_cast<const long*>(&EV8a[((2*s+1) << 5) + (g << 3)]);
            c00 = __builtin_amdgcn_mfma_f32_16x16x32_fp8_fp8(esA[0][2*s],   b0, c00, 0, 0, 0);
            c01 = __builtin_amdgcn_mfma_f32_16x16x32_fp8_fp8(esA[0][2*s+1], b1, c01, 0, 0, 0);
            c10 = __builtin_amdgcn_mfma_f32_16x16x32_fp8_fp8(esA[1][2*s],   b0, c10, 0, 0, 0);
            c11 = __builtin_amdgcn_mfma_f32_16x16x32_fp8_fp8(esA[1][2*s+1], b1, c11, 0, 0, 0);
        }
        const floatx4 ap0 = c00 + c01;
        const floatx4 ap1 = c10 + c11;

        float E0[4], E1[4];
        #pragma unroll
        for (int i = 0; i < 4; ++i) {
            E0[i] = 16.0f * rcp_nr(ap0[i] + tdv16);
            E1[i] = 16.0f * rcp_nr(ap1[i] + tdv16);
        }
        if (l15 < 4) {
            const float v0 = (l15 & 2) ? ((l15 & 1) ? E0[3] : E0[2])
                                       : ((l15 & 1) ? E0[1] : E0[0]);
            const float v1 = (l15 & 2) ? ((l15 & 1) ? E1[3] : E1[2])
                                       : ((l15 & 1) ? E1[1] : E1[0]);
            const int i0 = (w << 4) + (g << 2) + l15;
            EUa[i0]        = __builtin_bit_cast(unsigned short, (_Float16)v0);
            EU8a[i0]       = (unsigned char)f32_to_e4m3(v0 * 16.0f);
            EUa[i0 + 128]  = __builtin_bit_cast(unsigned short, (_Float16)v1);
            EU8a[i0 + 128] = (unsigned char)f32_to_e4m3(v1 * 16.0f);
        }
        float sU = ((E0[0] + E0[1]) + (E0[2] + E0[3]))
                 + ((E1[0] + E1[1]) + (E1[2] + E1[3]));
        sU = xor16_add(sU);
        sU += __shfl_xor(sU, 32, 64);
        if (l == 0) wsU[w] = sU;
        __syncthreads();

        float su = eud_s;
        {
            const floatx4* wu = reinterpret_cast<const floatx4*>(wsU);
            const floatx4 ss = wu[0] + wu[1];
            su += (ss[0] + ss[1]) + (ss[2] + ss[3]);
        }
        evd = Cs * rcp_nr(su);

        // q-phase
        floatx4 q00 = {0,0,0,0}, q01 = {0,0,0,0}, q10 = {0,0,0,0}, q11 = {0,0,0,0};
        #pragma unroll
        for (int s = 0; s < 4; ++s) {
            const long a0 = *reinterpret_cast<const long*>(&EU8a[((2*s) << 5) + (g << 3)]);
            const long a1 = *reinterpret_cast<const long*>(&EU8a[((2*s+1) << 5) + (g << 3)]);
            q00 = __builtin_amdgcn_mfma_f32_16x16x32_fp8_fp8(a0, esB[0][2*s],   q00, 0, 0, 0);
            q01 = __builtin_amdgcn_mfma_f32_16x16x32_fp8_fp8(a1, esB[0][2*s+1], q01, 0, 0, 0);
            q10 = __builtin_amdgcn_mfma_f32_16x16x32_fp8_fp8(a0, esB[1][2*s],   q10, 0, 0, 0);
            q11 = __builtin_amdgcn_mfma_f32_16x16x32_fp8_fp8(a1, esB[1][2*s+1], q11, 0, 0, 0);
        }
        const floatx4 aq0 = q00 + q01;
        const floatx4 aq1 = q10 + q11;

        const float EVv0 = 16.0f * rcp_nr(aq0[0] + tdu16);
        const float EVv1 = 16.0f * rcp_nr(aq1[0] + tdu16);
        if (l < 16) {
            EVa[(w << 4) + l]        = __builtin_bit_cast(unsigned short, (_Float16)EVv0);
            EV8a[(w << 4) + l]       = (unsigned char)f32_to_e4m3(EVv0 * 16.0f);
            EVa[(w << 4) + l + 128]  = __builtin_bit_cast(unsigned short, (_Float16)EVv1);
            EV8a[(w << 4) + l + 128] = (unsigned char)f32_to_e4m3(EVv1 * 16.0f);
        }
        float sV = reduce16(EVv0) + reduce16(EVv1);
        if (l == 0) wsV[w] = sV;
        __syncthreads();
    }

    // ---------- epilogue (v15 verbatim: fp8 fragment decode) ----------
    const int r0 = (w << 4) + l15;
    const int r1 = r0 + 128;
    const float Ud = flog2(eud_s);
    const float Vd = flog2(evd);
    const float Up0 = flog2((float)__builtin_bit_cast(_Float16, EUa[r0]));
    const float Up1 = flog2((float)__builtin_bit_cast(_Float16, EUa[r1]));
    const size_t ob = (size_t)bat * 66049;  // 257*257
    float* rp0 = out + ob + (size_t)r0 * 257;
    float* rp1 = out + ob + (size_t)r1 * 257;

    #pragma unroll
    for (int s = 0; s < 8; ++s) {
        const uint2v pa0 = __builtin_bit_cast(uint2v, esA[0][s]);
        const uint2v pa1 = __builtin_bit_cast(uint2v, esA[1][s]);
        const half8v vh = *reinterpret_cast<const half8v*>(&EVa[(s << 5) + (g << 3)]);
        const int c0 = (s << 5) + (g << 3);
        #pragma unroll
        for (int j = 0; j < 8; ++j) {
            const float vlog = flog2((float)vh[j]);
            const unsigned b0 = (pa0[j >> 2] >> ((j & 3) * 8)) & 255u;
            const unsigned b1 = (pa1[j >> 2] >> ((j & 3) * 8)) & 255u;
            rp0[c0 + j] = (flog2(dec_e4m3(b0)) + Up0 + vlog) * LN2;
            rp1[c0 + j] = (flog2(dec_e4m3(b1)) + Up1 + vlog) * LN2;
        }
    }
    if (l < 16) {
        rp0[256] = (alpha2 + Up0 + Vd) * LN2;
        rp1[256] = (alpha2 + Up1 + Vd) * LN2;
    }
    if (t < 257) {
        const float vp = (t < 256)
            ? flog2((float)__builtin_bit_cast(_Float16, EVa[t])) : Vd;
        out[ob + 65792 + t] = (alpha2 + Ud + vp) * LN2;
    }
}

extern "C" void kernel_launch(void* const* d_in, const int* in_sizes, int n_in,
                              void* d_out, int out_size, void* d_ws, size_t ws_size,
                              hipStream_t stream)
{
    const float* scores = (const float*)d_in[0];
    const float* alpha  = (const float*)d_in[1];
    const int*   iters  = (const int*)d_in[2];
    float* out = (float*)d_out;
    const int B = in_sizes[0] >> 16;
    hipLaunchKernelGGL(sinkhorn_kernel, dim3(B), dim3(512), 0, stream,
                       scores, alpha, iters, out);
}

// Round 17
// 102.838 us; speedup vs baseline: 1.8596x; 1.8596x over previous
//
#include <hip/hip_runtime.h>

// Sinkhorn (dustbin-augmented), MFMA edition v17 = v9 (measured best, 103us)
// with ONE change: the esT LDS layout. v9's packed col-major (512B stride)
// put every column's base in bank 0 and its XOR swizzle could not separate
// the four g-groups (cols 8 apart share col&7 AND bank base) -> 4.7M
// conflict-cycles (~7.5us/CU). New layout: stride 264 shorts (132 dwords ==
// 4 mod 32 -> neighbor cols spread across banks) + an 8-short pad keyed on
// (col>>3)&1 (separates g groups {0,2} from {1,3}). Shared eidx() at all
// four touchpoints; 16B alignment preserved; bijective within each column.
//
// Scaled exp-domain state (A = 2^{alpha*log2e}, Cs = 2^8/A):
//   EU_i  = 1/(sum_j es_ij*EV_j + A*evd)         es = 2^{s*log2e} (f16)
//   eud_s = Cs/(sum_j EV_j + evd)
//   EV_j  = 1/(sum_i es_ij*EU_i + A*eud_s)
//   evd'  = Cs/(sum_i EU_i + eud_s)
//   Z core = (log2 es + log2 EU + log2 EV)*ln2   (dustbins use alpha2)
//
// Fragment maps (proven v8..v13): wave w, lane l = l15 + 16g:
//   esA[s][j] = es[16w+l15][s*32+g*8+j]   (A operand, row strip)
//   esB[s][j] = es[s*32+g*8+j][16w+l15]   (B operand, col strip)
// C/D layout: col=lane&15, row=(lane>>4)*4+reg (HW-measured).

typedef _Float16 half8 __attribute__((ext_vector_type(8)));
typedef float floatx4 __attribute__((ext_vector_type(4)));

constexpr float L2E = 1.4426950408889634f;
constexpr float LN2 = 0.6931471805599453f;

__device__ __forceinline__ float flog2(float x) { return __builtin_amdgcn_logf(x); }
__device__ __forceinline__ float fexp2(float x) { return __builtin_amdgcn_exp2f(x); }

// 1/d via v_rcp_f32 + one Newton step (<=1 ulp, d>0)
__device__ __forceinline__ float rcp_nr(float d) {
    float r = __builtin_amdgcn_rcpf(d);
    return r * fmaf(-d, r, 2.0f);
}

template <int CTRL>
__device__ __forceinline__ float dpp_add(float x) {
    int y = __builtin_amdgcn_update_dpp(0, __builtin_bit_cast(int, x), CTRL, 0xF, 0xF, true);
    return x + __builtin_bit_cast(float, y);
}
// sum over the 16 lanes of each row (lanes l&15)
__device__ __forceinline__ float reduce16(float x) {
    x = dpp_add<0xB1>(x);    // xor 1
    x = dpp_add<0x4E>(x);    // xor 2
    x = dpp_add<0x124>(x);   // row_ror:4
    x = dpp_add<0x128>(x);   // row_ror:8
    return x;
}
__device__ __forceinline__ float xor16_add(float x) {
    int y = __builtin_amdgcn_ds_swizzle(__builtin_bit_cast(int, x), 0x401F);
    return x + __builtin_bit_cast(float, y);
}

// esT addressing: col-major, stride 264 shorts, XOR swizzle + g-group pad.
// r in [0,256) -> (r ^ ((col&7)<<3)) in [0,256), +pad(col) in {0,8} -> [0,264).
__device__ __forceinline__ int eidx(int col, int r) {
    return col * 264 + ((r ^ ((col & 7) << 3)) + (((col >> 3) & 1) << 3));
}

__global__ __launch_bounds__(1024)
__attribute__((amdgpu_waves_per_eu(4, 4)))
void sinkhorn_kernel(const float* __restrict__ scores,
                     const float* __restrict__ alpha_p,
                     const int* __restrict__ iters_p,
                     float* __restrict__ out)
{
    const int bat = blockIdx.x;
    const int t   = threadIdx.x;
    const int a   = t >> 5;         // prologue/epilogue: rows [8a, 8a+8)
    const int bb  = t & 31;         // prologue/epilogue: cols 4bb.. / 128+4bb..
    const int w   = t >> 6;         // wave 0..15
    const int l   = t & 63;
    const int g   = (t >> 4) & 3;   // k-group within wave
    const int l15 = t & 15;

    const float alpha2 = alpha_p[0] * L2E;
    const float A  = fexp2(alpha2);
    const float Cs = fexp2(8.0f - alpha2);   // 2^8 / A
    const int iters = iters_p[0];

    __shared__ __align__(16) unsigned short esT[256 * 264];  // 132 KB col-major
    __shared__ __align__(16) unsigned short EUa[272];
    __shared__ __align__(16) unsigned short EVa[272];
    __shared__ __align__(16) float wsU[16];
    __shared__ __align__(16) float wsV[16];

    // ---------------- prologue: load scores -> f16 es^T ----------------
    {
        const float* sp = scores + ((size_t)bat << 16) + ((size_t)a << 11) + (bb << 2);
        half8 cp[8];  // per-column packs of this thread's 8 rows
        #pragma unroll
        for (int r = 0; r < 8; ++r) {
            const float4 x0 = *reinterpret_cast<const float4*>(sp + (r << 8));
            const float4 x1 = *reinterpret_cast<const float4*>(sp + (r << 8) + 128);
            cp[0][r] = (_Float16)fexp2(x0.x * L2E);
            cp[1][r] = (_Float16)fexp2(x0.y * L2E);
            cp[2][r] = (_Float16)fexp2(x0.z * L2E);
            cp[3][r] = (_Float16)fexp2(x0.w * L2E);
            cp[4][r] = (_Float16)fexp2(x1.x * L2E);
            cp[5][r] = (_Float16)fexp2(x1.y * L2E);
            cp[6][r] = (_Float16)fexp2(x1.z * L2E);
            cp[7][r] = (_Float16)fexp2(x1.w * L2E);
        }
        #pragma unroll
        for (int ci = 0; ci < 8; ++ci) {
            const int col = (ci < 4) ? ((bb << 2) + ci) : (128 + (bb << 2) + ci - 4);
            *reinterpret_cast<half8*>(&esT[eidx(col, a << 3)]) = cp[ci];
        }
    }
    if (t < 256) EVa[t] = 0x3C00;      // EV = 1.0 (f16)
    if (t < 16)  wsV[t] = 16.0f;       // per-wave sum of 16 ones
    __syncthreads();

    // ---- persistent A-fragments: es row strip of wave w (asm-pinned) ----
    half8 esA[8];
    {
        const int m16 = (w << 4) + l15;
        #pragma unroll
        for (int s = 0; s < 8; ++s) {
            #pragma unroll
            for (int j = 0; j < 8; ++j) {
                const int col = (s << 5) + (g << 3) + j;
                esA[s][j] = __builtin_bit_cast(_Float16, esT[eidx(col, m16)]);
            }
            asm volatile("" : "+v"(esA[s]));  // opaque def: no remat
        }
    }
    // ---- persistent B-fragments: es col strip ----
    half8 esB[8];
    {
        const int colL = (w << 4) + l15;
        #pragma unroll
        for (int s = 0; s < 8; ++s) {
            esB[s] = *reinterpret_cast<const half8*>(
                &esT[eidx(colL, (s << 5) + (g << 3))]);
            asm volatile("" : "+v"(esB[s]));
        }
    }

    float evd = 1.0f, eud_s = 1.0f;

    const half8* evp = reinterpret_cast<const half8*>(EVa) + g;
    const half8* eup = reinterpret_cast<const half8*>(EUa) + g;

    for (int it = 0; it < iters; ++it) {
        // ---- scalars: eud_s from Sum(EV) + evd (all threads, redundant) ----
        float sv = evd;
        {
            const floatx4* wv = reinterpret_cast<const floatx4*>(wsV);
            floatx4 s0 = wv[0], s1 = wv[1], s2 = wv[2], s3 = wv[3];
            floatx4 ss = (s0 + s1) + (s2 + s3);
            sv += (ss[0] + ss[1]) + (ss[2] + ss[3]);
        }
        eud_s = Cs * rcp_nr(sv);
        const float tdu = A * eud_s;
        const float tdv = A * evd;

        // ---- p-phase: D[m][*] = sum_k es[m][k]*EV[k] (2x4 indep chains) ----
        floatx4 acc0 = {0.f, 0.f, 0.f, 0.f}, acc1 = {0.f, 0.f, 0.f, 0.f};
        #pragma unroll
        for (int s = 0; s < 4; ++s) {
            acc0 = __builtin_amdgcn_mfma_f32_16x16x32_f16(esA[2*s],   evp[(2*s) << 2],   acc0, 0, 0, 0);
            acc1 = __builtin_amdgcn_mfma_f32_16x16x32_f16(esA[2*s+1], evp[(2*s+1) << 2], acc1, 0, 0, 0);
        }
        floatx4 acc = acc0 + acc1;

        const float E0 = rcp_nr(acc[0] + tdv);
        const float E1 = rcp_nr(acc[1] + tdv);
        const float E2 = rcp_nr(acc[2] + tdv);
        const float E3 = rcp_nr(acc[3] + tdv);
        if (l15 < 4) {  // rows 16w + 4g + l15
            const float lo  = (l15 & 1) ? E1 : E0;
            const float hi  = (l15 & 1) ? E3 : E2;
            const float val = (l15 & 2) ? hi : lo;
            EUa[(w << 4) + (g << 2) + l15] =
                __builtin_bit_cast(unsigned short, (_Float16)val);
        }
        float sU = (E0 + E1) + (E2 + E3);
        sU = xor16_add(sU);
        sU += __shfl_xor(sU, 32, 64);
        if (l == 0) wsU[w] = sU;
        __syncthreads();

        // ---- scalars: evd' from Sum(EU) + eud_s ----
        float su = eud_s;
        {
            const floatx4* wu = reinterpret_cast<const floatx4*>(wsU);
            floatx4 s0 = wu[0], s1 = wu[1], s2 = wu[2], s3 = wu[3];
            floatx4 ss = (s0 + s1) + (s2 + s3);
            su += (ss[0] + ss[1]) + (ss[2] + ss[3]);
        }
        evd = Cs * rcp_nr(su);

        // ---- q-phase: D[*][n] = sum_k EU[k]*es[k][n] (2x4 indep chains) ----
        floatx4 q0 = {0.f, 0.f, 0.f, 0.f}, q1 = {0.f, 0.f, 0.f, 0.f};
        #pragma unroll
        for (int s = 0; s < 4; ++s) {
            q0 = __builtin_amdgcn_mfma_f32_16x16x32_f16(eup[(2*s) << 2],   esB[2*s],   q0, 0, 0, 0);
            q1 = __builtin_amdgcn_mfma_f32_16x16x32_f16(eup[(2*s+1) << 2], esB[2*s+1], q1, 0, 0, 0);
        }
        floatx4 acc2 = q0 + q1;

        const float EVv = rcp_nr(acc2[0] + tdu);   // col 16w+l15 (rows replicated)
        if (l < 16) EVa[(w << 4) + l] =
            __builtin_bit_cast(unsigned short, (_Float16)EVv);
        float sV = reduce16(EVv);
        if (l == 0) wsV[w] = sV;
        __syncthreads();
    }

    // ---------------- output: Z = (s' + u' + v' + 9-ish)*ln2 ----------------
    const float vdust = flog2(evd);
    const float udust = flog2(eud_s);
    float Up[8], Vp[8];
    int cols[8];
    #pragma unroll
    for (int r = 0; r < 8; ++r)
        Up[r] = flog2((float)__builtin_bit_cast(_Float16, EUa[(a << 3) + r]));
    #pragma unroll
    for (int ci = 0; ci < 8; ++ci) {
        cols[ci] = (ci < 4) ? ((bb << 2) + ci) : (128 + (bb << 2) + ci - 4);
        Vp[ci] = flog2((float)__builtin_bit_cast(_Float16, EVa[cols[ci]]));
    }
    const size_t ob = (size_t)bat * 66049;  // 257*257
    #pragma unroll
    for (int ci = 0; ci < 8; ++ci) {
        const int col = cols[ci];
        const half8 esc = *reinterpret_cast<const half8*>(&esT[eidx(col, a << 3)]);
        #pragma unroll
        for (int r = 0; r < 8; ++r) {
            out[ob + (size_t)((a << 3) + r) * 257 + col] =
                (flog2((float)esc[r]) + Up[r] + Vp[ci]) * LN2;
        }
    }
    if (bb == 0) {
        #pragma unroll
        for (int r = 0; r < 8; ++r)
            out[ob + (size_t)((a << 3) + r) * 257 + 256] =
                (alpha2 + Up[r] + vdust) * LN2;
    }
    if (t < 257) {
        const float vp = (t < 256)
            ? flog2((float)__builtin_bit_cast(_Float16, EVa[t])) : vdust;
        out[ob + 65792 + t] = (alpha2 + udust + vp) * LN2;
    }
}

extern "C" void kernel_launch(void* const* d_in, const int* in_sizes, int n_in,
                              void* d_out, int out_size, void* d_ws, size_t ws_size,
                              hipStream_t stream)
{
    const float* scores = (const float*)d_in[0];
    const float* alpha  = (const float*)d_in[1];
    const int*   iters  = (const int*)d_in[2];
    float* out = (float*)d_out;
    const int B = in_sizes[0] >> 16;
    hipLaunchKernelGGL(sinkhorn_kernel, dim3(B), dim3(1024), 0, stream,
                       scores, alpha, iters, out);
}